// Round 7
// baseline (290.747 us; speedup 1.0000x reference)
//
#include <hip/hip_runtime.h>
#include <math.h>

#define NPT 4096
#define NTOT 16384

// ---------------- K0: u[n][c] = sum_d w1[c][d]*s[n][d]; pack w14[c]=w1[c][4] ----
__global__ __launch_bounds__(256) void k0_u(const float* __restrict__ s,
                                            const float* __restrict__ w1,
                                            float* __restrict__ u,
                                            float* __restrict__ w14) {
  int gid = blockIdx.x * 256 + threadIdx.x;
  int n = gid >> 4;
  int c0 = (gid & 15) << 2;
  float4 sv = *(const float4*)(s + (size_t)n * 4);
  float uv[4];
#pragma unroll
  for (int i = 0; i < 4; ++i) {
    const float* wr = w1 + (size_t)(c0 + i) * 5;
    uv[i] = wr[0] * sv.x + wr[1] * sv.y + wr[2] * sv.z + wr[3] * sv.w;
  }
  float4 o; o.x = uv[0]; o.y = uv[1]; o.z = uv[2]; o.w = uv[3];
  *(float4*)(u + (size_t)n * 64 + c0) = o;
  if (blockIdx.x == 0 && threadIdx.x < 64)
    w14[threadIdx.x] = w1[threadIdx.x * 5 + 4];
}

// ---------------- K1: exact KNN, wave-per-row, LDS-staged, u64-key merge -------
// block: 256 thr = 4 waves = 4 rows (same batch). grid 4096.
// Lane l owns candidates m = i*64+l. 2-deep register mins + rare LDS rescan.
// 16 rounds of 64-lane u64-min butterfly; key = sortable(d2)<<32 | m
// == lex (d2, idx) == jax top_k lower-index tie-break.
__device__ __forceinline__ unsigned int fkey(float f) {
  unsigned int u = __float_as_uint(f);
  return u ^ ((unsigned int)((int)u >> 31) | 0x80000000u);
}

__global__ __launch_bounds__(256) void k1_knn(const float* __restrict__ s,
                                              unsigned short* __restrict__ knn) {
  __shared__ float2 xy[NPT];
  const int tid = threadIdx.x;
  const int lane = tid & 63;
  const int row = blockIdx.x * 4 + (tid >> 6);
  const int b = row >> 12, n = row & 4095;
  const float* sb = s + (size_t)b * NPT * 4;
  const float INF = __builtin_inff();

  // stage all 4096 xy pairs (32 KB) once per block
#pragma unroll
  for (int j = 0; j < 16; ++j) {
    int idx = tid + j * 256;
    xy[idx] = *(const float2*)(sb + (size_t)idx * 4);
  }
  __syncthreads();

  const float2 pn = xy[n];
  const float sqn = pn.x * pn.x + pn.y * pn.y;

  // distance phase: per-lane (min, 2nd-min); in-order arrival => strict '<'
  // preserves lowest-index tie-break within a lane.
  float m1v = INF, m2v = INF;
  int m1s = 0, m2s = 0;
#pragma unroll 8
  for (int i = 0; i < 64; ++i) {
    float2 pm = xy[i * 64 + lane];
    float sqm = pm.x * pm.x + pm.y * pm.y;
    float dot = pn.x * pm.x + pn.y * pm.y;
    float d2 = (sqn + sqm) - 2.f * dot;   // same expression as reference
    bool c1 = d2 < m1v;
    bool c2 = d2 < m2v;
    m2v = c1 ? m1v : (c2 ? d2 : m2v);
    m2s = c1 ? m1s : (c2 ? i : m2s);
    m1v = c1 ? d2 : m1v;
    m1s = c1 ? i : m1s;
  }

  unsigned long long lkey =
      ((unsigned long long)fkey(m1v) << 32) | (unsigned)(m1s * 64 + lane);
  unsigned long long k2b =
      ((unsigned long long)fkey(m2v) << 32) | (unsigned)(m2s * 64 + lane);
  bool have2 = true;
  unsigned long long emask = 0;

  for (int r = 0; r < 16; ++r) {          // dynamic: keep rescan un-replicated
    unsigned long long wk = lkey;
#pragma unroll
    for (int off = 32; off >= 1; off >>= 1) {
      unsigned long long ok =
          (unsigned long long)__shfl_xor((long long)wk, off, 64);
      wk = (ok < wk) ? ok : wk;
    }
    // all lanes hold the global lex-min key; lane r emits its index
    unsigned int m = (unsigned int)wk & 4095u;
    if (lane == r) knn[(size_t)row * 16 + r] = (unsigned short)m;
    // owner lane exposes its next-best unemitted candidate
    if ((int)((unsigned int)wk & 63u) == lane) {
      emask |= 1ull << (m >> 6);
      if (have2) {
        lkey = k2b; have2 = false;
      } else {
        float bv = INF; int bs = 0;
        for (int i = 0; i < 64; ++i) {     // rare: recompute from LDS
          if ((emask >> i) & 1ull) continue;
          float2 pm = xy[i * 64 + lane];
          float sqm = pm.x * pm.x + pm.y * pm.y;
          float dot = pn.x * pm.x + pn.y * pm.y;
          float d2 = (sqn + sqm) - 2.f * dot;
          bool bet = d2 < bv;
          bv = bet ? d2 : bv;
          bs = bet ? i : bs;
        }
        lkey = ((unsigned long long)fkey(bv) << 32) | (unsigned)(bs * 64 + lane);
      }
    }
  }
}

// ---------------- K2: edge MLP h1 -> h2 -> max-pool; writes node rows ----------
// block: 256 thr, 8 points (128 edge-rows). grid 2048.
#define DOT4ACC(acc, hv, wv) \
  acc = fmaf((hv).x, (wv).x, fmaf((hv).y, (wv).y, fmaf((hv).z, (wv).z, fmaf((hv).w, (wv).w, acc))))

__global__ __launch_bounds__(256) void k2_edge(
    const float* __restrict__ s, const float* __restrict__ g,
    const float* __restrict__ b1, const float* __restrict__ w2g,
    const float* __restrict__ b2, const float* __restrict__ u,
    const float* __restrict__ w14, const unsigned short* __restrict__ knn,
    float* __restrict__ node) {
  __shared__ float h1T[128 * 68];
  __shared__ float w2T[128 * 68];
  const int tid = threadIdx.x;

  // stage w2 (128x64) into [o][68]
  for (int gi = tid; gi < 2048; gi += 256) {
    int o = gi >> 4, ct = gi & 15;
    float4 v = *(const float4*)(w2g + (size_t)gi * 4);
    *(float4*)(w2T + o * 68 + ct * 4) = v;
  }

  // producer: h1[row][c] = relu((u_n[c]+b1[c]) - u_m[c] + eye*w14[c])
  {
    const int row = tid >> 1, half = tid & 1, c0 = half * 32;
    const int p = row >> 4, k = row & 15;
    const int n_pt = blockIdx.x * 8 + p;
    const int n_in = n_pt & 4095;
    const int base_b = n_pt - n_in;
    int m_in = knn[(size_t)n_pt * 16 + k] & 4095;
    const float eye = (m_in == n_in) ? 1.f : 0.f;
    const float* un = u + (size_t)n_pt * 64 + c0;
    const float* um = u + (size_t)(base_b + m_in) * 64 + c0;
#pragma unroll
    for (int t = 0; t < 8; ++t) {
      float4 a   = *(const float4*)(un + t * 4);
      float4 bb  = *(const float4*)(um + t * 4);
      float4 b1v = *(const float4*)(b1 + c0 + t * 4);
      float4 wv  = *(const float4*)(w14 + c0 + t * 4);
      float4 h;
      h.x = fmaxf(fmaf(eye, wv.x, (a.x + b1v.x) - bb.x), 0.f);
      h.y = fmaxf(fmaf(eye, wv.y, (a.y + b1v.y) - bb.y), 0.f);
      h.z = fmaxf(fmaf(eye, wv.z, (a.z + b1v.z) - bb.z), 0.f);
      h.w = fmaxf(fmaf(eye, wv.w, (a.w + b1v.w) - bb.w), 0.f);
      *(float4*)(h1T + row * 68 + c0 + t * 4) = h;
    }
  }
  __syncthreads();

  // consumer: thread (p = tid>>5, oh = tid&31) owns o = oh + 32j, j<4; 16 k-rows
  {
    const int p = tid >> 5, oh = tid & 31;
    const int n_pt = blockIdx.x * 8 + p;
    float4 acc[16];
    float4 binit;
    binit.x = b2[oh]; binit.y = b2[oh + 32]; binit.z = b2[oh + 64]; binit.w = b2[oh + 96];
#pragma unroll
    for (int kk = 0; kk < 16; ++kk) acc[kk] = binit;

#pragma unroll 4
    for (int ct = 0; ct < 16; ++ct) {
      float4 w0 = *(const float4*)(w2T + (oh      ) * 68 + ct * 4);
      float4 w1v = *(const float4*)(w2T + (oh + 32) * 68 + ct * 4);
      float4 w2v = *(const float4*)(w2T + (oh + 64) * 68 + ct * 4);
      float4 w3v = *(const float4*)(w2T + (oh + 96) * 68 + ct * 4);
#pragma unroll
      for (int kk = 0; kk < 16; ++kk) {
        float4 hv = *(const float4*)(h1T + (p * 16 + kk) * 68 + ct * 4);
        DOT4ACC(acc[kk].x, hv, w0);
        DOT4ACC(acc[kk].y, hv, w1v);
        DOT4ACC(acc[kk].z, hv, w2v);
        DOT4ACC(acc[kk].w, hv, w3v);
      }
    }
    float4 f = acc[0];
#pragma unroll
    for (int kk = 1; kk < 16; ++kk) {
      f.x = fmaxf(f.x, acc[kk].x); f.y = fmaxf(f.y, acc[kk].y);
      f.z = fmaxf(f.z, acc[kk].z); f.w = fmaxf(f.w, acc[kk].w);
    }
    f.x = fmaxf(f.x, 0.f); f.y = fmaxf(f.y, 0.f);
    f.z = fmaxf(f.z, 0.f); f.w = fmaxf(f.w, 0.f);
    float* nrow = node + (size_t)n_pt * 132;
    nrow[oh] = f.x; nrow[oh + 32] = f.y; nrow[oh + 64] = f.z; nrow[oh + 96] = f.w;
    if (oh == 0) {
      float4 sv = *(const float4*)(s + (size_t)n_pt * 4);
      float2 gv = *(const float2*)(g + (size_t)n_pt * 2);
      nrow[128] = sv.x - gv.x; nrow[129] = sv.y - gv.y;
      nrow[130] = sv.z; nrow[131] = sv.w;
    }
  }
}

// ---------------- K3: node MLP 132->64->128->64->4 + sigmoid -------------------
// block: 256 thr, 32 points. grid 512.
__global__ __launch_bounds__(256) void k3_node(
    const float* __restrict__ node,
    const float* __restrict__ fw1, const float* __restrict__ fb1,
    const float* __restrict__ fw2, const float* __restrict__ fb2,
    const float* __restrict__ fw3, const float* __restrict__ fb3,
    const float* __restrict__ fw4, const float* __restrict__ fb4,
    float* __restrict__ out) {
  __shared__ float bufA[32 * 136];
  __shared__ float bufB[32 * 136];
  __shared__ float wb[64 * 136];
  const int tid = threadIdx.x;
  const int n0 = blockIdx.x * 32;
  const int p = tid >> 3, og = tid & 7;

  // stage node rows (132 f32 each) and fw1 (64x132 -> stride 136)
  for (int gi = tid; gi < 32 * 33; gi += 256) {
    int r = gi / 33, ct = gi - r * 33;
    *(float4*)(bufA + r * 136 + ct * 4) = *(const float4*)(node + (size_t)(n0 + r) * 132 + ct * 4);
  }
  for (int gi = tid; gi < 64 * 33; gi += 256) {
    int r = gi / 33, ct = gi - r * 33;
    *(float4*)(wb + r * 136 + ct * 4) = *(const float4*)(fw1 + (size_t)r * 132 + ct * 4);
  }
  __syncthreads();

  // L1: 132 -> 64  (8 outputs/thread, o = og + 8j)
  {
    float acc[8];
#pragma unroll
    for (int j = 0; j < 8; ++j) acc[j] = fb1[og + 8 * j];
    for (int ct = 0; ct < 33; ++ct) {
      float4 in4 = *(const float4*)(bufA + p * 136 + ct * 4);
#pragma unroll
      for (int j = 0; j < 8; ++j) {
        float4 w4 = *(const float4*)(wb + (og + 8 * j) * 136 + ct * 4);
        DOT4ACC(acc[j], in4, w4);
      }
    }
#pragma unroll
    for (int j = 0; j < 8; ++j) bufB[p * 136 + og + 8 * j] = fmaxf(acc[j], 0.f);
  }
  __syncthreads();
  for (int gi = tid; gi < 128 * 16; gi += 256) {  // fw2: 128x64 -> stride 68
    int r = gi >> 4, ct = gi & 15;
    *(float4*)(wb + r * 68 + ct * 4) = *(const float4*)(fw2 + (size_t)r * 64 + ct * 4);
  }
  __syncthreads();

  // L2: 64 -> 128  (16 outputs/thread)
  {
    float acc[16];
#pragma unroll
    for (int j = 0; j < 16; ++j) acc[j] = fb2[og + 8 * j];
    for (int ct = 0; ct < 16; ++ct) {
      float4 in4 = *(const float4*)(bufB + p * 136 + ct * 4);
#pragma unroll
      for (int j = 0; j < 16; ++j) {
        float4 w4 = *(const float4*)(wb + (og + 8 * j) * 68 + ct * 4);
        DOT4ACC(acc[j], in4, w4);
      }
    }
#pragma unroll
    for (int j = 0; j < 16; ++j) bufA[p * 136 + og + 8 * j] = fmaxf(acc[j], 0.f);
  }
  __syncthreads();
  for (int gi = tid; gi < 64 * 32; gi += 256) {  // fw3: 64x128 -> stride 132
    int r = gi >> 5, ct = gi & 31;
    *(float4*)(wb + r * 132 + ct * 4) = *(const float4*)(fw3 + (size_t)r * 128 + ct * 4);
  }
  __syncthreads();

  // L3: 128 -> 64  (8 outputs/thread)
  {
    float acc[8];
#pragma unroll
    for (int j = 0; j < 8; ++j) acc[j] = fb3[og + 8 * j];
    for (int ct = 0; ct < 32; ++ct) {
      float4 in4 = *(const float4*)(bufA + p * 136 + ct * 4);
#pragma unroll
      for (int j = 0; j < 8; ++j) {
        float4 w4 = *(const float4*)(wb + (og + 8 * j) * 132 + ct * 4);
        DOT4ACC(acc[j], in4, w4);
      }
    }
#pragma unroll
    for (int j = 0; j < 8; ++j) bufB[p * 136 + og + 8 * j] = fmaxf(acc[j], 0.f);
  }
  __syncthreads();
  for (int gi = tid; gi < 4 * 16; gi += 256) {  // fw4: 4x64 -> stride 68
    int r = gi >> 4, ct = gi & 15;
    *(float4*)(wb + r * 68 + ct * 4) = *(const float4*)(fw4 + (size_t)r * 64 + ct * 4);
  }
  __syncthreads();

  // L4: 64 -> 4, then out = 2*sigmoid(z) - 1
  if (tid < 128) {
    const int pp = tid >> 2, o = tid & 3;
    float acc = fb4[o];
    for (int ct = 0; ct < 16; ++ct) {
      float4 in4 = *(const float4*)(bufB + pp * 136 + ct * 4);
      float4 w4 = *(const float4*)(wb + o * 68 + ct * 4);
      DOT4ACC(acc, in4, w4);
    }
    float sgm = 1.f / (1.f + expf(-acc));
    out[(size_t)(n0 + pp) * 4 + o] = fmaf(2.f, sgm, -1.f);
  }
}

// ---------------- launch -------------------------------------------------------
extern "C" void kernel_launch(void* const* d_in, const int* in_sizes, int n_in,
                              void* d_out, int out_size, void* d_ws, size_t ws_size,
                              hipStream_t stream) {
  (void)in_sizes; (void)n_in; (void)out_size; (void)ws_size;
  const float* s   = (const float*)d_in[0];
  const float* g   = (const float*)d_in[1];
  const float* w1  = (const float*)d_in[2];
  const float* b1  = (const float*)d_in[3];
  const float* w2  = (const float*)d_in[4];
  const float* b2  = (const float*)d_in[5];
  const float* fw1 = (const float*)d_in[6];
  const float* fb1 = (const float*)d_in[7];
  const float* fw2 = (const float*)d_in[8];
  const float* fb2 = (const float*)d_in[9];
  const float* fw3 = (const float*)d_in[10];
  const float* fb3 = (const float*)d_in[11];
  const float* fw4 = (const float*)d_in[12];
  const float* fb4 = (const float*)d_in[13];

  float* ws   = (float*)d_ws;
  float* u    = ws;                                    // 16384*64 = 1048576 f32
  float* w14  = ws + 1048576;                          // 64 f32
  unsigned short* knn16 = (unsigned short*)(ws + 1048576 + 64);  // 262144 u16
  float* node = ws + 1048576 + 64 + 131072;            // 16384*132 f32
  float* out  = (float*)d_out;

  k0_u   <<<1024, 256, 0, stream>>>(s, w1, u, w14);
  k1_knn <<<4096, 256, 0, stream>>>(s, knn16);
  k2_edge<<<2048, 256, 0, stream>>>(s, g, b1, w2, b2, u, w14, knn16, node);
  k3_node<<<512,  256, 0, stream>>>(node, fw1, fb1, fw2, fb2, fw3, fb3, fw4, fb4, out);
}

// Round 14
// 234.564 us; speedup vs baseline: 1.2395x; 1.2395x over previous
//
#include <hip/hip_runtime.h>
#include <math.h>

#define NPT 4096
#define NTOT 16384

// ---------------- K0: u[n][c] = sum_d w1[c][d]*s[n][d]; pack w14[c]=w1[c][4] ----
__global__ __launch_bounds__(256) void k0_u(const float* __restrict__ s,
                                            const float* __restrict__ w1,
                                            float* __restrict__ u,
                                            float* __restrict__ w14) {
  int gid = blockIdx.x * 256 + threadIdx.x;
  int n = gid >> 4;
  int c0 = (gid & 15) << 2;
  float4 sv = *(const float4*)(s + (size_t)n * 4);
  float uv[4];
#pragma unroll
  for (int i = 0; i < 4; ++i) {
    const float* wr = w1 + (size_t)(c0 + i) * 5;
    uv[i] = wr[0] * sv.x + wr[1] * sv.y + wr[2] * sv.z + wr[3] * sv.w;
  }
  float4 o; o.x = uv[0]; o.y = uv[1]; o.z = uv[2]; o.w = uv[3];
  *(float4*)(u + (size_t)n * 64 + c0) = o;
  if (blockIdx.x == 0 && threadIdx.x < 64)
    w14[threadIdx.x] = w1[threadIdx.x * 5 + 4];
}

// ---------------- K1: exact KNN, wave-per-row, DPP-min merge (no DS in merge) --
// block: 256 thr = 4 waves = 4 rows. grid 4096. xy staged in LDS (32 KB).
// Lane l owns candidates m = i*64+l; keeps sorted top-3 in regs; rare exact
// rescan (P~0.7%/row) from LDS with exclusion mask. 16 rounds: wave min-f32 of
// d2 via DPP (6 VALU), then masked wave min-u32 of m for exact lower-index
// tie-break == jax top_k semantics.
#define DPP_STEP_F(ctrl)                                                      \
  {                                                                           \
    float t_ = __int_as_float(__builtin_amdgcn_update_dpp(                    \
        __float_as_int(v), __float_as_int(v), ctrl, 0xf, 0xf, false));        \
    v = fminf(v, t_);                                                         \
  }
__device__ __forceinline__ float wave_min_f32(float v) {
  DPP_STEP_F(0x111) DPP_STEP_F(0x112) DPP_STEP_F(0x114) DPP_STEP_F(0x118)
  DPP_STEP_F(0x142) DPP_STEP_F(0x143)
  return __int_as_float(__builtin_amdgcn_readlane(__float_as_int(v), 63));
}
#define DPP_STEP_U(ctrl)                                                      \
  {                                                                           \
    unsigned t_ = (unsigned)__builtin_amdgcn_update_dpp(                      \
        (int)v, (int)v, ctrl, 0xf, 0xf, false);                               \
    v = (t_ < v) ? t_ : v;                                                    \
  }
__device__ __forceinline__ unsigned wave_min_u32(unsigned v) {
  DPP_STEP_U(0x111) DPP_STEP_U(0x112) DPP_STEP_U(0x114) DPP_STEP_U(0x118)
  DPP_STEP_U(0x142) DPP_STEP_U(0x143)
  return (unsigned)__builtin_amdgcn_readlane((int)v, 63);
}

__global__ __launch_bounds__(256) void k1_knn(const float* __restrict__ s,
                                              unsigned short* __restrict__ knn) {
  __shared__ float2 xy[NPT];
  const int tid = threadIdx.x;
  const int lane = tid & 63;
  const int row = blockIdx.x * 4 + (tid >> 6);
  const int b = row >> 12, n = row & 4095;
  const float* sb = s + (size_t)b * NPT * 4;
  const float INF = __builtin_inff();

  // stage all 4096 xy pairs (32 KB) once per block
#pragma unroll
  for (int j = 0; j < 16; ++j) {
    int idx = tid + j * 256;
    xy[idx] = *(const float2*)(sb + (size_t)idx * 4);
  }
  __syncthreads();

  const float2 pn = xy[n];
  const float sqn = pn.x * pn.x + pn.y * pn.y;

  // scan: per-lane sorted top-3 (branchless). strict '<' + ascending i keeps
  // lowest-index-first on equal d2 (matches top_k tie-break within a lane).
  float s1k = INF, s2k = INF, s3k = INF;
  unsigned s1m = 0, s2m = 0, s3m = 0;
#pragma unroll 8
  for (int i = 0; i < 64; ++i) {
    const unsigned m = (unsigned)(i * 64 + lane);
    float2 pm = xy[m];
    float sqm = pm.x * pm.x + pm.y * pm.y;
    float dot = pn.x * pm.x + pn.y * pm.y;
    float d2 = (sqn + sqm) - 2.f * dot;   // same expression as before
    bool c1 = d2 < s1k, c2 = d2 < s2k, c3 = d2 < s3k;
    s3k = c2 ? s2k : (c3 ? d2 : s3k);  s3m = c2 ? s2m : (c3 ? m : s3m);
    s2k = c1 ? s1k : (c2 ? d2 : s2k);  s2m = c1 ? s1m : (c2 ? m : s2m);
    s1k = c1 ? d2 : s1k;               s1m = c1 ? m : s1m;
  }

  unsigned long long imask = 0;  // i-blocks already emitted by this lane

  for (int r = 0; r < 16; ++r) {
    float kmin = wave_min_f32(s1k);
    bool ismin = (s1k == kmin);            // v_min_f32 returns an input exactly
    unsigned mc = ismin ? s1m : 0xFFFFFFFFu;
    unsigned mstar = wave_min_u32(mc);     // exact lower-index tie-break
    if (lane == r) knn[(size_t)row * 16 + r] = (unsigned short)mstar;
    if (ismin && s1m == mstar) {           // unique owner (m globally unique)
      imask |= 1ull << (s1m >> 6);
      s1k = s2k; s1m = s2m; s2k = s3k; s2m = s3m; s3k = INF; s3m = 0;
      if (s1k == INF) {                    // rare (~0.7%/row): exact rescan
        float bk = INF; unsigned bm = 0;
        for (int i = 0; i < 64; ++i) {
          if ((imask >> i) & 1ull) continue;
          unsigned m = (unsigned)(i * 64 + lane);
          float2 pm = xy[m];
          float sqm = pm.x * pm.x + pm.y * pm.y;
          float dot = pn.x * pm.x + pn.y * pm.y;
          float d2 = (sqn + sqm) - 2.f * dot;
          bool bet = d2 < bk;
          bk = bet ? d2 : bk;
          bm = bet ? m : bm;
        }
        s1k = bk; s1m = bm;
      }
    }
  }
}

// ---------------- K2: edge MLP h1 -> h2 -> max-pool; writes node rows ----------
// block: 256 thr, 8 points (128 edge-rows). grid 2048.
#define DOT4ACC(acc, hv, wv) \
  acc = fmaf((hv).x, (wv).x, fmaf((hv).y, (wv).y, fmaf((hv).z, (wv).z, fmaf((hv).w, (wv).w, acc))))

__global__ __launch_bounds__(256) void k2_edge(
    const float* __restrict__ s, const float* __restrict__ g,
    const float* __restrict__ b1, const float* __restrict__ w2g,
    const float* __restrict__ b2, const float* __restrict__ u,
    const float* __restrict__ w14, const unsigned short* __restrict__ knn,
    float* __restrict__ node) {
  __shared__ float h1T[128 * 68];
  __shared__ float w2T[128 * 68];
  const int tid = threadIdx.x;

  // stage w2 (128x64) into [o][68]
  for (int gi = tid; gi < 2048; gi += 256) {
    int o = gi >> 4, ct = gi & 15;
    float4 v = *(const float4*)(w2g + (size_t)gi * 4);
    *(float4*)(w2T + o * 68 + ct * 4) = v;
  }

  // producer: h1[row][c] = relu((u_n[c]+b1[c]) - u_m[c] + eye*w14[c])
  {
    const int row = tid >> 1, half = tid & 1, c0 = half * 32;
    const int p = row >> 4, k = row & 15;
    const int n_pt = blockIdx.x * 8 + p;
    const int n_in = n_pt & 4095;
    const int base_b = n_pt - n_in;
    int m_in = knn[(size_t)n_pt * 16 + k] & 4095;
    const float eye = (m_in == n_in) ? 1.f : 0.f;
    const float* un = u + (size_t)n_pt * 64 + c0;
    const float* um = u + (size_t)(base_b + m_in) * 64 + c0;
#pragma unroll
    for (int t = 0; t < 8; ++t) {
      float4 a   = *(const float4*)(un + t * 4);
      float4 bb  = *(const float4*)(um + t * 4);
      float4 b1v = *(const float4*)(b1 + c0 + t * 4);
      float4 wv  = *(const float4*)(w14 + c0 + t * 4);
      float4 h;
      h.x = fmaxf(fmaf(eye, wv.x, (a.x + b1v.x) - bb.x), 0.f);
      h.y = fmaxf(fmaf(eye, wv.y, (a.y + b1v.y) - bb.y), 0.f);
      h.z = fmaxf(fmaf(eye, wv.z, (a.z + b1v.z) - bb.z), 0.f);
      h.w = fmaxf(fmaf(eye, wv.w, (a.w + b1v.w) - bb.w), 0.f);
      *(float4*)(h1T + row * 68 + c0 + t * 4) = h;
    }
  }
  __syncthreads();

  // consumer: thread (p = tid>>5, oh = tid&31) owns o = oh + 32j, j<4; 16 k-rows
  {
    const int p = tid >> 5, oh = tid & 31;
    const int n_pt = blockIdx.x * 8 + p;
    float4 acc[16];
    float4 binit;
    binit.x = b2[oh]; binit.y = b2[oh + 32]; binit.z = b2[oh + 64]; binit.w = b2[oh + 96];
#pragma unroll
    for (int kk = 0; kk < 16; ++kk) acc[kk] = binit;

#pragma unroll 4
    for (int ct = 0; ct < 16; ++ct) {
      float4 w0 = *(const float4*)(w2T + (oh      ) * 68 + ct * 4);
      float4 w1v = *(const float4*)(w2T + (oh + 32) * 68 + ct * 4);
      float4 w2v = *(const float4*)(w2T + (oh + 64) * 68 + ct * 4);
      float4 w3v = *(const float4*)(w2T + (oh + 96) * 68 + ct * 4);
#pragma unroll
      for (int kk = 0; kk < 16; ++kk) {
        float4 hv = *(const float4*)(h1T + (p * 16 + kk) * 68 + ct * 4);
        DOT4ACC(acc[kk].x, hv, w0);
        DOT4ACC(acc[kk].y, hv, w1v);
        DOT4ACC(acc[kk].z, hv, w2v);
        DOT4ACC(acc[kk].w, hv, w3v);
      }
    }
    float4 f = acc[0];
#pragma unroll
    for (int kk = 1; kk < 16; ++kk) {
      f.x = fmaxf(f.x, acc[kk].x); f.y = fmaxf(f.y, acc[kk].y);
      f.z = fmaxf(f.z, acc[kk].z); f.w = fmaxf(f.w, acc[kk].w);
    }
    f.x = fmaxf(f.x, 0.f); f.y = fmaxf(f.y, 0.f);
    f.z = fmaxf(f.z, 0.f); f.w = fmaxf(f.w, 0.f);
    float* nrow = node + (size_t)n_pt * 132;
    nrow[oh] = f.x; nrow[oh + 32] = f.y; nrow[oh + 64] = f.z; nrow[oh + 96] = f.w;
    if (oh == 0) {
      float4 sv = *(const float4*)(s + (size_t)n_pt * 4);
      float2 gv = *(const float2*)(g + (size_t)n_pt * 2);
      nrow[128] = sv.x - gv.x; nrow[129] = sv.y - gv.y;
      nrow[130] = sv.z; nrow[131] = sv.w;
    }
  }
}

// ---------------- K3: node MLP 132->64->128->64->4 + sigmoid -------------------
// block: 256 thr, 32 points. grid 512.
__global__ __launch_bounds__(256) void k3_node(
    const float* __restrict__ node,
    const float* __restrict__ fw1, const float* __restrict__ fb1,
    const float* __restrict__ fw2, const float* __restrict__ fb2,
    const float* __restrict__ fw3, const float* __restrict__ fb3,
    const float* __restrict__ fw4, const float* __restrict__ fb4,
    float* __restrict__ out) {
  __shared__ float bufA[32 * 136];
  __shared__ float bufB[32 * 136];
  __shared__ float wb[64 * 136];
  const int tid = threadIdx.x;
  const int n0 = blockIdx.x * 32;
  const int p = tid >> 3, og = tid & 7;

  // stage node rows (132 f32 each) and fw1 (64x132 -> stride 136)
  for (int gi = tid; gi < 32 * 33; gi += 256) {
    int r = gi / 33, ct = gi - r * 33;
    *(float4*)(bufA + r * 136 + ct * 4) = *(const float4*)(node + (size_t)(n0 + r) * 132 + ct * 4);
  }
  for (int gi = tid; gi < 64 * 33; gi += 256) {
    int r = gi / 33, ct = gi - r * 33;
    *(float4*)(wb + r * 136 + ct * 4) = *(const float4*)(fw1 + (size_t)r * 132 + ct * 4);
  }
  __syncthreads();

  // L1: 132 -> 64  (8 outputs/thread, o = og + 8j)
  {
    float acc[8];
#pragma unroll
    for (int j = 0; j < 8; ++j) acc[j] = fb1[og + 8 * j];
    for (int ct = 0; ct < 33; ++ct) {
      float4 in4 = *(const float4*)(bufA + p * 136 + ct * 4);
#pragma unroll
      for (int j = 0; j < 8; ++j) {
        float4 w4 = *(const float4*)(wb + (og + 8 * j) * 136 + ct * 4);
        DOT4ACC(acc[j], in4, w4);
      }
    }
#pragma unroll
    for (int j = 0; j < 8; ++j) bufB[p * 136 + og + 8 * j] = fmaxf(acc[j], 0.f);
  }
  __syncthreads();
  for (int gi = tid; gi < 128 * 16; gi += 256) {  // fw2: 128x64 -> stride 68
    int r = gi >> 4, ct = gi & 15;
    *(float4*)(wb + r * 68 + ct * 4) = *(const float4*)(fw2 + (size_t)r * 64 + ct * 4);
  }
  __syncthreads();

  // L2: 64 -> 128  (16 outputs/thread)
  {
    float acc[16];
#pragma unroll
    for (int j = 0; j < 16; ++j) acc[j] = fb2[og + 8 * j];
    for (int ct = 0; ct < 16; ++ct) {
      float4 in4 = *(const float4*)(bufB + p * 136 + ct * 4);
#pragma unroll
      for (int j = 0; j < 16; ++j) {
        float4 w4 = *(const float4*)(wb + (og + 8 * j) * 68 + ct * 4);
        DOT4ACC(acc[j], in4, w4);
      }
    }
#pragma unroll
    for (int j = 0; j < 16; ++j) bufA[p * 136 + og + 8 * j] = fmaxf(acc[j], 0.f);
  }
  __syncthreads();
  for (int gi = tid; gi < 64 * 32; gi += 256) {  // fw3: 64x128 -> stride 132
    int r = gi >> 5, ct = gi & 31;
    *(float4*)(wb + r * 132 + ct * 4) = *(const float4*)(fw3 + (size_t)r * 128 + ct * 4);
  }
  __syncthreads();

  // L3: 128 -> 64  (8 outputs/thread)
  {
    float acc[8];
#pragma unroll
    for (int j = 0; j < 8; ++j) acc[j] = fb3[og + 8 * j];
    for (int ct = 0; ct < 32; ++ct) {
      float4 in4 = *(const float4*)(bufA + p * 136 + ct * 4);
#pragma unroll
      for (int j = 0; j < 8; ++j) {
        float4 w4 = *(const float4*)(wb + (og + 8 * j) * 132 + ct * 4);
        DOT4ACC(acc[j], in4, w4);
      }
    }
#pragma unroll
    for (int j = 0; j < 8; ++j) bufB[p * 136 + og + 8 * j] = fmaxf(acc[j], 0.f);
  }
  __syncthreads();
  for (int gi = tid; gi < 4 * 16; gi += 256) {  // fw4: 4x64 -> stride 68
    int r = gi >> 4, ct = gi & 15;
    *(float4*)(wb + r * 68 + ct * 4) = *(const float4*)(fw4 + (size_t)r * 64 + ct * 4);
  }
  __syncthreads();

  // L4: 64 -> 4, then out = 2*sigmoid(z) - 1
  if (tid < 128) {
    const int pp = tid >> 2, o = tid & 3;
    float acc = fb4[o];
    for (int ct = 0; ct < 16; ++ct) {
      float4 in4 = *(const float4*)(bufB + pp * 136 + ct * 4);
      float4 w4 = *(const float4*)(wb + o * 68 + ct * 4);
      DOT4ACC(acc, in4, w4);
    }
    float sgm = 1.f / (1.f + expf(-acc));
    out[(size_t)(n0 + pp) * 4 + o] = fmaf(2.f, sgm, -1.f);
  }
}

// ---------------- launch -------------------------------------------------------
extern "C" void kernel_launch(void* const* d_in, const int* in_sizes, int n_in,
                              void* d_out, int out_size, void* d_ws, size_t ws_size,
                              hipStream_t stream) {
  (void)in_sizes; (void)n_in; (void)out_size; (void)ws_size;
  const float* s   = (const float*)d_in[0];
  const float* g   = (const float*)d_in[1];
  const float* w1  = (const float*)d_in[2];
  const float* b1  = (const float*)d_in[3];
  const float* w2  = (const float*)d_in[4];
  const float* b2  = (const float*)d_in[5];
  const float* fw1 = (const float*)d_in[6];
  const float* fb1 = (const float*)d_in[7];
  const float* fw2 = (const float*)d_in[8];
  const float* fb2 = (const float*)d_in[9];
  const float* fw3 = (const float*)d_in[10];
  const float* fb3 = (const float*)d_in[11];
  const float* fw4 = (const float*)d_in[12];
  const float* fb4 = (const float*)d_in[13];

  float* ws   = (float*)d_ws;
  float* u    = ws;                                    // 16384*64 = 1048576 f32
  float* w14  = ws + 1048576;                          // 64 f32
  unsigned short* knn16 = (unsigned short*)(ws + 1048576 + 64);  // 262144 u16
  float* node = ws + 1048576 + 64 + 131072;            // 16384*132 f32
  float* out  = (float*)d_out;

  k0_u   <<<1024, 256, 0, stream>>>(s, w1, u, w14);
  k1_knn <<<4096, 256, 0, stream>>>(s, knn16);
  k2_edge<<<2048, 256, 0, stream>>>(s, g, b1, w2, b2, u, w14, knn16, node);
  k3_node<<<512,  256, 0, stream>>>(node, fw1, fb1, fw2, fb2, fw3, fb3, fw4, fb4, out);
}